// Round 2
// baseline (1359.239 us; speedup 1.0000x reference)
//
#include <hip/hip_runtime.h>
#include <hip/hip_bf16.h>

#define NB    16384   // batch
#define NR    2048    // memory rows
#define NC    128     // memory cols (= key dim)
#define KCTRL 1024    // controller dim
#define NH    134     // NC + 6
#define EPSF  1e-16f
#define ESTR  2080    // E_s row stride in bf16: 2048+32 -> +64B -> 16-bank shift per row

__device__ __forceinline__ float softplus_f(float x) {
    return fmaxf(x, 0.f) + log1pf(__expf(-fabsf(x)));
}

// ---------------- K0: M row norms ----------------
__global__ __launch_bounds__(64) void mnorm_kernel(const float* __restrict__ M,
                                                   float* __restrict__ mnorm) {
    const int i = blockIdx.x;
    const int lane = threadIdx.x;
    float a = M[(size_t)i * NC + lane];
    float b = M[(size_t)i * NC + 64 + lane];
    float s = a * a + b * b;
    #pragma unroll
    for (int m = 1; m < 64; m <<= 1) s += __shfl_xor(s, m);
    if (lane == 0) mnorm[i] = sqrtf(s);
}

// ---------------- K1: h = x @ W_fc + b_fc ----------------
// 8 batch rows per block; thread j owns output column j. W loads are
// software-prefetched one k-group ahead to hide L2 latency; x reads are
// wave-uniform (scalar loads).
__global__ __launch_bounds__(192) void fc_kernel(const float* __restrict__ x,
                                                 const float* __restrict__ Wfc,
                                                 const float* __restrict__ bfc,
                                                 float* __restrict__ k_buf,
                                                 float* __restrict__ h6) {
    const int b0 = blockIdx.x * 8;
    const int j = threadIdx.x;
    if (j >= NH) return;

    float acc[8];
    #pragma unroll
    for (int r = 0; r < 8; r++) acc[r] = 0.f;

    const float* W0 = Wfc + j;
    float w0 = W0[0], w1 = W0[NH], w2 = W0[2 * NH], w3 = W0[3 * NH];

    #pragma unroll 2
    for (int k = 0; k < KCTRL; k += 4) {
        const int kn = (k + 4) & (KCTRL - 1);   // wraps to 0 on last iter (unused)
        const float* Wn = Wfc + (size_t)kn * NH + j;
        const float n0 = Wn[0], n1 = Wn[NH], n2 = Wn[2 * NH], n3 = Wn[3 * NH];
        #pragma unroll
        for (int r = 0; r < 8; r++) {
            const float4 xv = *(const float4*)(x + (size_t)(b0 + r) * KCTRL + k);
            acc[r] = fmaf(xv.x, w0, acc[r]);
            acc[r] = fmaf(xv.y, w1, acc[r]);
            acc[r] = fmaf(xv.z, w2, acc[r]);
            acc[r] = fmaf(xv.w, w3, acc[r]);
        }
        w0 = n0; w1 = n1; w2 = n2; w3 = n3;
    }
    const float bb = bfc[j];
    #pragma unroll
    for (int r = 0; r < 8; r++) {
        float v = acc[r] + bb;
        if (j < NC) k_buf[(size_t)(b0 + r) * NC + j] = v;
        else        h6[(size_t)(b0 + r) * 6 + (j - NC)] = v;
    }
}

// ---------------- K2: per-row scalars ----------------
// scal[b][8] = {beta, g, s0, s1, s2, gamma, knorm, 0}
__global__ __launch_bounds__(64) void scal_kernel(const float* __restrict__ k_buf,
                                                  const float* __restrict__ h6,
                                                  float* __restrict__ scal) {
    const int b = blockIdx.x;
    const int lane = threadIdx.x;
    float a = k_buf[(size_t)b * NC + lane];
    float c = k_buf[(size_t)b * NC + 64 + lane];
    float s = a * a + c * c;
    #pragma unroll
    for (int m = 1; m < 64; m <<= 1) s += __shfl_xor(s, m);
    if (lane == 0) {
        const float* h = h6 + (size_t)b * 6;
        float beta = softplus_f(h[0]);
        float g = 1.f / (1.f + __expf(-h[1]));
        float m3 = fmaxf(h[2], fmaxf(h[3], h[4]));
        float e0 = __expf(h[2] - m3), e1 = __expf(h[3] - m3), e2 = __expf(h[4] - m3);
        float inv = 1.f / (e0 + e1 + e2);
        float gamma = 1.f + softplus_f(h[5]);
        float* sc = scal + (size_t)b * 8;
        sc[0] = beta; sc[1] = g; sc[2] = e0 * inv; sc[3] = e1 * inv;
        sc[4] = e2 * inv; sc[5] = gamma; sc[6] = sqrtf(s); sc[7] = 0.f;
    }
}

// ---------------- K3: fused head ----------------
// 8 batch rows per block, 256 threads.
// Phase 1  : E[tb][i] = exp(beta * cossim(k_tb, M_i))  (bf16 in LDS), S = sum E
// Phase 1.5: interleaved mapping — lane l of group tbg handles i = 32n+l.
//            E reads are consecutive-bf16 (conflict-free, row pad shifts groups
//            16 banks apart); wprev reads coalesced. w_pow kept in packed-bf16
//            registers, written back after the read loop (one lockstep wave
//            group owns each row -> no cross-thread hazard).
// Phase 2  : r[tb][:] = (w_pow @ M) / Z
__global__ __launch_bounds__(256) void head_kernel(const float* __restrict__ M,
                                                   const float* __restrict__ mnorm,
                                                   const float* __restrict__ k_buf,
                                                   const float* __restrict__ scal,
                                                   const float* __restrict__ wprev,
                                                   float* __restrict__ out) {
    __shared__ __hip_bfloat16 E_s[8][ESTR];   // 33280 B
    __shared__ float scal_s[8][8];
    __shared__ float wred[8][4];
    __shared__ float fac_a[8], fac_c[8], invZ_s[8];

    const int tid = threadIdx.x;
    const int b0 = blockIdx.x * 8;

    if (tid < 64) scal_s[tid >> 3][tid & 7] = scal[(size_t)(b0 + (tid >> 3)) * 8 + (tid & 7)];
    __syncthreads();

    // ---- phase 1 ----
    float Sp[8];
    #pragma unroll
    for (int tb = 0; tb < 8; tb++) Sp[tb] = 0.f;

    for (int ot = 0; ot < 4; ot++) {
        const int ia = tid + 512 * ot;
        const int ib = ia + 256;
        const float mna = mnorm[ia], mnb = mnorm[ib];
        float da[8], db[8];
        #pragma unroll
        for (int tb = 0; tb < 8; tb++) { da[tb] = 0.f; db[tb] = 0.f; }
        const float* Ma = M + (size_t)ia * NC;
        const float* Mb = M + (size_t)ib * NC;
        for (int c = 0; c < NC; c += 4) {
            const float4 a4 = *(const float4*)(Ma + c);
            const float4 b4 = *(const float4*)(Mb + c);
            #pragma unroll
            for (int tb = 0; tb < 8; tb++) {
                const float4 k4 = *(const float4*)(k_buf + (size_t)(b0 + tb) * NC + c);
                da[tb] = fmaf(k4.x, a4.x, da[tb]); da[tb] = fmaf(k4.y, a4.y, da[tb]);
                da[tb] = fmaf(k4.z, a4.z, da[tb]); da[tb] = fmaf(k4.w, a4.w, da[tb]);
                db[tb] = fmaf(k4.x, b4.x, db[tb]); db[tb] = fmaf(k4.y, b4.y, db[tb]);
                db[tb] = fmaf(k4.z, b4.z, db[tb]); db[tb] = fmaf(k4.w, b4.w, db[tb]);
            }
        }
        #pragma unroll
        for (int tb = 0; tb < 8; tb++) {
            const float beta = scal_s[tb][0], knorm = scal_s[tb][6];
            const float ea = __expf(beta * da[tb] / (knorm * mna + EPSF));
            const float eb = __expf(beta * db[tb] / (knorm * mnb + EPSF));
            E_s[tb][ia] = __float2bfloat16(ea);
            E_s[tb][ib] = __float2bfloat16(eb);
            Sp[tb] += ea + eb;
        }
    }
    #pragma unroll
    for (int tb = 0; tb < 8; tb++) {
        #pragma unroll
        for (int m = 1; m < 64; m <<= 1) Sp[tb] += __shfl_xor(Sp[tb], m);
    }
    if ((tid & 63) == 0) {
        const int w = tid >> 6;
        #pragma unroll
        for (int tb = 0; tb < 8; tb++) wred[tb][w] = Sp[tb];
    }
    __syncthreads();
    if (tid < 8) {
        const float S = wred[tid][0] + wred[tid][1] + wred[tid][2] + wred[tid][3];
        const float g = scal_s[tid][1];
        fac_a[tid] = g / S;
        fac_c[tid] = 1.f - g;
    }
    __syncthreads();

    // ---- phase 1.5: w_tilde^gamma, interleaved mapping ----
    {
        const int tbg  = tid >> 5;          // row 0..7 (one 32-lane group per row)
        const int lane = tid & 31;
        const float s0 = scal_s[tbg][2], s1 = scal_s[tbg][3], s2 = scal_s[tbg][4];
        const float gm = scal_s[tbg][5];
        const float fa = fac_a[tbg], fcm = fac_c[tbg];
        const float* wp = wprev + (size_t)(b0 + tbg) * NR;

        float Zp = 0.f;
        unsigned pwp[32];                   // 64 bf16 w_pow values, packed
        #pragma unroll
        for (int n = 0; n < 64; n++) {
            const int i   = n * 32 + lane;
            const int im1 = (i + NR - 1) & (NR - 1);
            const int ip1 = (i + 1) & (NR - 1);
            const float em1 = __bfloat162float(E_s[tbg][im1]);
            const float e0  = __bfloat162float(E_s[tbg][i]);
            const float ep1 = __bfloat162float(E_s[tbg][ip1]);
            const float wgm1 = fmaf(fa, em1, fcm * wp[im1]);
            const float wg0  = fmaf(fa, e0,  fcm * wp[i]);
            const float wgp1 = fmaf(fa, ep1, fcm * wp[ip1]);
            const float wt = fmaf(s0, wgm1, fmaf(s1, wg0, s2 * wgp1)) + EPSF;
            const float pw = __expf(gm * __logf(wt));   // wt > 0 always
            Zp += pw;
            __hip_bfloat16 hb = __float2bfloat16(pw);
            const unsigned u = *(unsigned short*)&hb;
            if (n & 1) pwp[n >> 1] |= (u << 16);
            else       pwp[n >> 1]  = u;
        }
        // write-back: all reads of row tbg (this wave group only) are done
        #pragma unroll
        for (int m = 0; m < 32; m++) {
            unsigned short lo = (unsigned short)(pwp[m] & 0xffffu);
            unsigned short hi = (unsigned short)(pwp[m] >> 16);
            E_s[tbg][64 * m + lane]      = *(__hip_bfloat16*)&lo;
            E_s[tbg][64 * m + 32 + lane] = *(__hip_bfloat16*)&hi;
        }
        #pragma unroll
        for (int m = 1; m < 32; m <<= 1) Zp += __shfl_xor(Zp, m);
        if (lane == 0) invZ_s[tbg] = 1.f / Zp;
    }
    __syncthreads();

    // ---- phase 2: r = (w_pow @ M) * invZ ----
    {
        const int jj = (tid & 63) << 1;      // 2 output cols
        const int tbA = (tid >> 6) << 1;     // 2 batch rows
        const int tbB = tbA + 1;
        float aA0 = 0.f, aA1 = 0.f, aB0 = 0.f, aB1 = 0.f;
        for (int i = 0; i < NR; i += 2) {
            const float2 m0 = *(const float2*)(M + (size_t)i * NC + jj);
            const float2 m1 = *(const float2*)(M + (size_t)(i + 1) * NC + jj);
            const __hip_bfloat162 evA = *(const __hip_bfloat162*)(&E_s[tbA][i]);
            const __hip_bfloat162 evB = *(const __hip_bfloat162*)(&E_s[tbB][i]);
            const float eA0 = __low2float(evA), eA1 = __high2float(evA);
            const float eB0 = __low2float(evB), eB1 = __high2float(evB);
            aA0 = fmaf(eA0, m0.x, aA0); aA1 = fmaf(eA0, m0.y, aA1);
            aA0 = fmaf(eA1, m1.x, aA0); aA1 = fmaf(eA1, m1.y, aA1);
            aB0 = fmaf(eB0, m0.x, aB0); aB1 = fmaf(eB0, m0.y, aB1);
            aB0 = fmaf(eB1, m1.x, aB0); aB1 = fmaf(eB1, m1.y, aB1);
        }
        const float zA = invZ_s[tbA], zB = invZ_s[tbB];
        float2 oA; oA.x = aA0 * zA; oA.y = aA1 * zA;
        float2 oB; oB.x = aB0 * zB; oB.y = aB1 * zB;
        *(float2*)(out + (size_t)(b0 + tbA) * NC + jj) = oA;
        *(float2*)(out + (size_t)(b0 + tbB) * NC + jj) = oB;
    }
}

extern "C" void kernel_launch(void* const* d_in, const int* in_sizes, int n_in,
                              void* d_out, int out_size, void* d_ws, size_t ws_size,
                              hipStream_t stream) {
    const float* x     = (const float*)d_in[0];
    const float* Wfc   = (const float*)d_in[1];
    const float* bfc   = (const float*)d_in[2];
    const float* M     = (const float*)d_in[3];
    const float* wprev = (const float*)d_in[4];
    float* out = (float*)d_out;

    char* ws = (char*)d_ws;
    float* k_buf = (float*)(ws);                       // 16384*128*4  = 8388608
    float* h6    = (float*)(ws + 8388608);             // 16384*6*4    = 393216
    float* scal  = (float*)(ws + 8781824);             // 16384*8*4    = 524288
    float* mnorm = (float*)(ws + 9306112);             // 2048*4       = 8192

    hipLaunchKernelGGL(mnorm_kernel, dim3(NR), dim3(64), 0, stream, M, mnorm);
    hipLaunchKernelGGL(fc_kernel, dim3(NB / 8), dim3(192), 0, stream, x, Wfc, bfc, k_buf, h6);
    hipLaunchKernelGGL(scal_kernel, dim3(NB), dim3(64), 0, stream, k_buf, h6, scal);
    hipLaunchKernelGGL(head_kernel, dim3(NB / 8), dim3(256), 0, stream,
                       M, mnorm, k_buf, scal, wprev, out);
}

// Round 3
// 507.319 us; speedup vs baseline: 2.6793x; 2.6793x over previous
//
#include <hip/hip_runtime.h>
#include <hip/hip_bf16.h>

#define NB    16384   // batch
#define NR    2048    // memory rows
#define NC    128     // memory cols (= key dim)
#define KCTRL 1024    // controller dim
#define NHP   144     // padded head cols (134 -> 144)
#define EPSF  1e-16f
#define ESTR  2056    // E_s row stride (bf16): 2048 + 8 -> 4112 B, 16B-aligned

typedef __attribute__((ext_vector_type(8))) short bf16x8;
typedef __attribute__((ext_vector_type(4))) float f32x4;

__device__ __forceinline__ float softplus_f(float x) {
    return fmaxf(x, 0.f) + log1pf(__expf(-fabsf(x)));
}
__device__ __forceinline__ unsigned short f2bf(float f) {
    __hip_bfloat16 h = __float2bfloat16(f);
    return *(unsigned short*)&h;
}
__device__ __forceinline__ float bf2f(unsigned short u) {
    __hip_bfloat16 h;
    *(unsigned short*)&h = u;
    return __bfloat162float(h);
}

// ---------------- P0: M -> M_bf16, M_T_bf16, mnorm ----------------
__global__ __launch_bounds__(64) void prep_m(const float* __restrict__ M,
                                             unsigned short* __restrict__ Mb,
                                             unsigned short* __restrict__ Mt,
                                             float* __restrict__ mnorm) {
    const int i = blockIdx.x;
    const int l = threadIdx.x;
    const float v0 = M[(size_t)i * NC + l];
    const float v1 = M[(size_t)i * NC + 64 + l];
    Mb[(size_t)i * NC + l]      = f2bf(v0);
    Mb[(size_t)i * NC + 64 + l] = f2bf(v1);
    Mt[(size_t)l * NR + i]        = f2bf(v0);
    Mt[(size_t)(64 + l) * NR + i] = f2bf(v1);
    float s = v0 * v0 + v1 * v1;
    #pragma unroll
    for (int m = 1; m < 64; m <<= 1) s += __shfl_xor(s, m);
    if (l == 0) mnorm[i] = sqrtf(s);
}

// ---------------- P1: W_fc -> W_T bf16 [NHP][KCTRL] ----------------
__global__ __launch_bounds__(64) void prep_w(const float* __restrict__ W,
                                             unsigned short* __restrict__ Wt) {
    const int k = blockIdx.x;     // 0..1023
    const int l = threadIdx.x;
    const float a = W[(size_t)k * 134 + l];
    const float b = W[(size_t)k * 134 + 64 + l];
    Wt[(size_t)l * KCTRL + k]        = f2bf(a);
    Wt[(size_t)(64 + l) * KCTRL + k] = f2bf(b);
    if (l < 6) {
        const float c = W[(size_t)k * 134 + 128 + l];
        Wt[(size_t)(128 + l) * KCTRL + k] = f2bf(c);
    }
}

// ---------------- K1: h = x @ W_fc + b_fc via MFMA; also scal ----------------
// 16 batch rows per block, 256 threads (4 waves). Wave w owns n-tiles {w, w+4},
// wave 0 additionally tile 8 (cols 128..143; cols>=134 are garbage, discarded).
// Epilogue computes knorm + all per-row scalars -> scal[b][8].
__global__ __launch_bounds__(256) void fc_mfma(const float* __restrict__ x,
                                               const unsigned short* __restrict__ Wt,
                                               const float* __restrict__ bfc,
                                               unsigned short* __restrict__ k_bf,
                                               float* __restrict__ scal) {
    __shared__ float ksum[16];
    __shared__ float h6s[16][6];

    const int tid  = threadIdx.x;
    const int w    = tid >> 6;
    const int lane = tid & 63;
    const int quad = lane >> 4;
    const int l16  = lane & 15;
    const int b0   = blockIdx.x * 16;

    if (tid < 16) ksum[tid] = 0.f;
    __syncthreads();

    const int t0 = w, t1 = w + 4;
    f32x4 acc0 = {0.f, 0.f, 0.f, 0.f};
    f32x4 acc1 = {0.f, 0.f, 0.f, 0.f};
    f32x4 acc2 = {0.f, 0.f, 0.f, 0.f};

    const float* xp = x + (size_t)(b0 + l16) * KCTRL + quad * 8;
    const unsigned short* w0p = Wt + (size_t)(t0 * 16 + l16) * KCTRL + quad * 8;
    const unsigned short* w1p = Wt + (size_t)(t1 * 16 + l16) * KCTRL + quad * 8;
    const unsigned short* w2p = Wt + (size_t)(128 + l16) * KCTRL + quad * 8;

    for (int k0 = 0; k0 < KCTRL; k0 += 32) {
        const float4 xa = *(const float4*)(xp + k0);
        const float4 xb = *(const float4*)(xp + k0 + 4);
        bf16x8 af;
        af[0] = (short)f2bf(xa.x); af[1] = (short)f2bf(xa.y);
        af[2] = (short)f2bf(xa.z); af[3] = (short)f2bf(xa.w);
        af[4] = (short)f2bf(xb.x); af[5] = (short)f2bf(xb.y);
        af[6] = (short)f2bf(xb.z); af[7] = (short)f2bf(xb.w);
        const bf16x8 bf0 = *(const bf16x8*)(w0p + k0);
        const bf16x8 bf1 = *(const bf16x8*)(w1p + k0);
        acc0 = __builtin_amdgcn_mfma_f32_16x16x32_bf16(af, bf0, acc0, 0, 0, 0);
        acc1 = __builtin_amdgcn_mfma_f32_16x16x32_bf16(af, bf1, acc1, 0, 0, 0);
        if (w == 0) {
            const bf16x8 bf2 = *(const bf16x8*)(w2p + k0);
            acc2 = __builtin_amdgcn_mfma_f32_16x16x32_bf16(af, bf2, acc2, 0, 0, 0);
        }
    }

    // epilogue: bias, write k_bf16, accumulate k^2 sums
    const float bb0 = bfc[t0 * 16 + l16];
    const float bb1 = bfc[t1 * 16 + l16];
    float p0[4], p1[4];
    #pragma unroll
    for (int reg = 0; reg < 4; reg++) {
        const int m = quad * 4 + reg;
        const float v0 = acc0[reg] + bb0;
        const float v1 = acc1[reg] + bb1;
        k_bf[(size_t)(b0 + m) * NC + t0 * 16 + l16] = f2bf(v0);
        k_bf[(size_t)(b0 + m) * NC + t1 * 16 + l16] = f2bf(v1);
        p0[reg] = v0 * v0; p1[reg] = v1 * v1;
    }
    #pragma unroll
    for (int s = 1; s < 16; s <<= 1) {
        #pragma unroll
        for (int reg = 0; reg < 4; reg++) {
            p0[reg] += __shfl_xor(p0[reg], s);
            p1[reg] += __shfl_xor(p1[reg], s);
        }
    }
    if (l16 == 0) {
        #pragma unroll
        for (int reg = 0; reg < 4; reg++) {
            atomicAdd(&ksum[quad * 4 + reg], p0[reg] + p1[reg]);
        }
    }
    if (w == 0 && l16 < 6) {
        const float bb2 = bfc[128 + l16];
        #pragma unroll
        for (int reg = 0; reg < 4; reg++) {
            h6s[quad * 4 + reg][l16] = acc2[reg] + bb2;
        }
    }
    __syncthreads();

    if (tid < 16) {
        const int m = tid;
        const float kn = sqrtf(ksum[m]);
        const float* h = h6s[m];
        const float beta = softplus_f(h[0]);
        const float g = 1.f / (1.f + __expf(-h[1]));
        const float m3 = fmaxf(h[2], fmaxf(h[3], h[4]));
        const float e0 = __expf(h[2] - m3), e1 = __expf(h[3] - m3), e2 = __expf(h[4] - m3);
        const float inv = 1.f / (e0 + e1 + e2);
        const float gamma = 1.f + softplus_f(h[5]);
        float* sc = scal + (size_t)(b0 + m) * 8;
        sc[0] = beta; sc[1] = g; sc[2] = e0 * inv; sc[3] = e1 * inv;
        sc[4] = e2 * inv; sc[5] = gamma; sc[6] = kn; sc[7] = 0.f;
    }
}

// ---------------- K2: fused head (MFMA) ----------------
// 16 batch rows per block, 256 threads (4 waves).
// Phase 1 : sim = k @ M^T via MFMA; E = exp(beta*sim) -> LDS bf16 (row-major);
//           S = sum E per row.
// Phase 1.5: per-row 16-lane groups; w_g neighbors exchanged via shfl;
//           w_pow written in place (reads of chunk n+1 precede writes of n).
// Phase 2 : r = (w_pow @ M) * invZ via MFMA (A from LDS, B = M_T from L2).
__global__ __launch_bounds__(256) void head_mfma(const unsigned short* __restrict__ Mb,
                                                 const unsigned short* __restrict__ Mt,
                                                 const float* __restrict__ mnorm,
                                                 const unsigned short* __restrict__ k_bf,
                                                 const float* __restrict__ scal,
                                                 const float* __restrict__ wprev,
                                                 float* __restrict__ out) {
    __shared__ __align__(16) unsigned short E_s[16][ESTR];   // 65792 B
    __shared__ float scal_s[16][8];
    __shared__ float wred[16][4];
    __shared__ float fa_s[16], fc_s[16], invZ_s[16];

    const int tid  = threadIdx.x;
    const int w    = tid >> 6;
    const int lane = tid & 63;
    const int quad = lane >> 4;
    const int l16  = lane & 15;
    const int b0   = blockIdx.x * 16;

    if (tid < 128) scal_s[tid >> 3][tid & 7] = scal[(size_t)(b0 + (tid >> 3)) * 8 + (tid & 7)];
    __syncthreads();

    // ---- phase 1 ----
    float betas[4], kns[4];
    #pragma unroll
    for (int reg = 0; reg < 4; reg++) {
        betas[reg] = scal_s[quad * 4 + reg][0];
        kns[reg]   = scal_s[quad * 4 + reg][6];
    }
    const unsigned short* ap = k_bf + (size_t)(b0 + l16) * NC + quad * 8;
    float Sp[4] = {0.f, 0.f, 0.f, 0.f};

    for (int t = 0; t < 32; t++) {
        const int n0 = (w * 32 + t) * 16;
        f32x4 acc = {0.f, 0.f, 0.f, 0.f};
        const unsigned short* bp = Mb + (size_t)(n0 + l16) * NC + quad * 8;
        #pragma unroll
        for (int k0 = 0; k0 < NC; k0 += 32) {
            const bf16x8 af = *(const bf16x8*)(ap + k0);
            const bf16x8 bf = *(const bf16x8*)(bp + k0);
            acc = __builtin_amdgcn_mfma_f32_16x16x32_bf16(af, bf, acc, 0, 0, 0);
        }
        const float mn = mnorm[n0 + l16];
        #pragma unroll
        for (int reg = 0; reg < 4; reg++) {
            const int m = quad * 4 + reg;
            const float sim = acc[reg] / (kns[reg] * mn + EPSF);
            const float e = __expf(betas[reg] * sim);
            E_s[m][n0 + l16] = f2bf(e);
            Sp[reg] += e;
        }
    }
    #pragma unroll
    for (int s = 1; s < 16; s <<= 1) {
        #pragma unroll
        for (int reg = 0; reg < 4; reg++) Sp[reg] += __shfl_xor(Sp[reg], s);
    }
    if (l16 == 0) {
        #pragma unroll
        for (int reg = 0; reg < 4; reg++) wred[quad * 4 + reg][w] = Sp[reg];
    }
    __syncthreads();
    if (tid < 16) {
        const float S = wred[tid][0] + wred[tid][1] + wred[tid][2] + wred[tid][3];
        const float g = scal_s[tid][1];
        fa_s[tid] = g / S;
        fc_s[tid] = 1.f - g;
    }
    __syncthreads();

    // ---- phase 1.5 ----
    {
        const int row = w * 4 + quad;            // one 16-lane group per row
        const float s0 = scal_s[row][2], s1 = scal_s[row][3], s2 = scal_s[row][4];
        const float gmm = scal_s[row][5];
        const float fa = fa_s[row], fcm = fc_s[row];
        const float* wp = wprev + (size_t)(b0 + row) * NR;
        const int lb = quad * 16;                // group base lane
        const int srcL = lb + ((l16 + 15) & 15);
        const int srcR = lb + ((l16 + 1) & 15);

        float g_first = fmaf(fa, bf2f(E_s[row][l16]), fcm * wp[l16]);
        float gm = fmaf(fa, bf2f(E_s[row][2032 + l16]), fcm * wp[2032 + l16]);
        float gc = g_first;
        float Zp = 0.f;
        for (int n = 0; n < 128; n++) {
            float gp;
            if (n < 127) {
                const int ip = (n + 1) * 16 + l16;
                gp = fmaf(fa, bf2f(E_s[row][ip]), fcm * wp[ip]);
            } else {
                gp = g_first;
            }
            const float lv  = __shfl(gc, srcL);
            const float lv2 = __shfl(gm, srcL);
            const float left = (l16 == 0) ? lv2 : lv;
            const float rv  = __shfl(gc, srcR);
            const float rv2 = __shfl(gp, srcR);
            const float right = (l16 == 15) ? rv2 : rv;
            const float wt = fmaf(s0, left, fmaf(s1, gc, s2 * right)) + EPSF;
            const float pw = __expf(gmm * __logf(wt));
            Zp += pw;
            E_s[row][n * 16 + l16] = f2bf(pw);   // chunk n+1 already read above
            gm = gc; gc = gp;
        }
        #pragma unroll
        for (int s = 1; s < 16; s <<= 1) Zp += __shfl_xor(Zp, s);
        if (l16 == 0) invZ_s[row] = 1.f / Zp;
    }
    __syncthreads();

    // ---- phase 2 ----
    {
        const int n0a = w * 16;
        const int n0b = 64 + w * 16;
        f32x4 accA = {0.f, 0.f, 0.f, 0.f};
        f32x4 accB = {0.f, 0.f, 0.f, 0.f};
        const unsigned short* bpa = Mt + (size_t)(n0a + l16) * NR + quad * 8;
        const unsigned short* bpb = Mt + (size_t)(n0b + l16) * NR + quad * 8;
        for (int k0 = 0; k0 < NR; k0 += 32) {
            const bf16x8 af = *(const bf16x8*)(&E_s[l16][k0 + quad * 8]);
            const bf16x8 ba = *(const bf16x8*)(bpa + k0);
            const bf16x8 bb = *(const bf16x8*)(bpb + k0);
            accA = __builtin_amdgcn_mfma_f32_16x16x32_bf16(af, ba, accA, 0, 0, 0);
            accB = __builtin_amdgcn_mfma_f32_16x16x32_bf16(af, bb, accB, 0, 0, 0);
        }
        #pragma unroll
        for (int reg = 0; reg < 4; reg++) {
            const int m = quad * 4 + reg;
            const float iz = invZ_s[m];
            out[(size_t)(b0 + m) * NC + n0a + l16] = accA[reg] * iz;
            out[(size_t)(b0 + m) * NC + n0b + l16] = accB[reg] * iz;
        }
    }
}

extern "C" void kernel_launch(void* const* d_in, const int* in_sizes, int n_in,
                              void* d_out, int out_size, void* d_ws, size_t ws_size,
                              hipStream_t stream) {
    const float* x     = (const float*)d_in[0];
    const float* Wfc   = (const float*)d_in[1];
    const float* bfc   = (const float*)d_in[2];
    const float* M     = (const float*)d_in[3];
    const float* wprev = (const float*)d_in[4];
    float* out = (float*)d_out;

    char* ws = (char*)d_ws;
    unsigned short* k_bf = (unsigned short*)(ws);              // 16384*128*2 = 4194304
    float*          scal = (float*)(ws + 4194304);             // 16384*8*4   = 524288
    float*          mnorm= (float*)(ws + 4718592);             // 2048*4      = 8192
    unsigned short* Mb   = (unsigned short*)(ws + 4726784);    // 2048*128*2  = 524288
    unsigned short* Mt   = (unsigned short*)(ws + 5251072);    // 128*2048*2  = 524288
    unsigned short* Wt   = (unsigned short*)(ws + 5775360);    // 144*1024*2  = 294912

    hipLaunchKernelGGL(prep_m, dim3(NR), dim3(64), 0, stream, M, Mb, Mt, mnorm);
    hipLaunchKernelGGL(prep_w, dim3(KCTRL), dim3(64), 0, stream, Wfc, Wt);
    hipLaunchKernelGGL(fc_mfma, dim3(NB / 16), dim3(256), 0, stream, x, Wt, bfc, k_bf, scal);
    hipLaunchKernelGGL(head_mfma, dim3(NB / 16), dim3(256), 0, stream,
                       Mb, Mt, mnorm, k_bf, scal, wprev, out);
}

// Round 4
// 387.731 us; speedup vs baseline: 3.5056x; 1.3084x over previous
//
#include <hip/hip_runtime.h>
#include <hip/hip_bf16.h>

#define NB    16384   // batch
#define NR    2048    // memory rows
#define NC    128     // memory cols (= key dim)
#define KCTRL 1024    // controller dim
#define EPSF  1e-16f
#define ESTR  2056    // E_s row stride (bf16): 2048 + 8 -> 4112 B, 16B-aligned

typedef __attribute__((ext_vector_type(8))) short bf16x8;
typedef __attribute__((ext_vector_type(4))) float f32x4;

__device__ __forceinline__ float softplus_f(float x) {
    return fmaxf(x, 0.f) + log1pf(__expf(-fabsf(x)));
}
__device__ __forceinline__ unsigned short f2bf(float f) {
    __hip_bfloat16 h = __float2bfloat16(f);
    return *(unsigned short*)&h;
}
__device__ __forceinline__ float bf2f(unsigned short u) {
    __hip_bfloat16 h;
    *(unsigned short*)&h = u;
    return __bfloat162float(h);
}

// ---------------- P0: M -> M_bf16, M_T_bf16, inv-norm ----------------
__global__ __launch_bounds__(64) void prep_m(const float* __restrict__ M,
                                             unsigned short* __restrict__ Mb,
                                             unsigned short* __restrict__ Mt,
                                             float* __restrict__ imn) {
    const int i = blockIdx.x;
    const int l = threadIdx.x;
    const float v0 = M[(size_t)i * NC + l];
    const float v1 = M[(size_t)i * NC + 64 + l];
    Mb[(size_t)i * NC + l]      = f2bf(v0);
    Mb[(size_t)i * NC + 64 + l] = f2bf(v1);
    Mt[(size_t)l * NR + i]        = f2bf(v0);
    Mt[(size_t)(64 + l) * NR + i] = f2bf(v1);
    float s = v0 * v0 + v1 * v1;
    #pragma unroll
    for (int m = 1; m < 64; m <<= 1) s += __shfl_xor(s, m);
    if (l == 0) imn[i] = 1.f / sqrtf(s);
}

// ---------------- P1: W_fc -> W_T bf16 [144][KCTRL] (rows 134..143 unwritten) ----
__global__ __launch_bounds__(64) void prep_w(const float* __restrict__ W,
                                             unsigned short* __restrict__ Wt) {
    const int k = blockIdx.x;     // 0..1023
    const int l = threadIdx.x;
    const float a = W[(size_t)k * 134 + l];
    const float b = W[(size_t)k * 134 + 64 + l];
    Wt[(size_t)l * KCTRL + k]        = f2bf(a);
    Wt[(size_t)(64 + l) * KCTRL + k] = f2bf(b);
    if (l < 6) {
        const float c = W[(size_t)k * 134 + 128 + l];
        Wt[(size_t)(128 + l) * KCTRL + k] = f2bf(c);
    }
}

// ---------------- K1: h = x @ W_fc + b_fc via MFMA (K split across waves) ----
// 16 batch rows / block, 256 threads. Wave w reduces K in [w*256,(w+1)*256)
// over all 9 column tiles (independent MFMA chains -> ILP, no redundant x reads).
// Cross-wave reduce in LDS, then epilogue: k_bf16, knorm, per-row scalars.
// scal[b][8] = {beta/knorm, g, s0, s1, s2, gamma, -, -}
__global__ __launch_bounds__(256) void fc_mfma(const float* __restrict__ x,
                                               const unsigned short* __restrict__ Wt,
                                               const float* __restrict__ bfc,
                                               unsigned short* __restrict__ k_bf,
                                               float* __restrict__ scal) {
    __shared__ float red[4][16][148];   // 37888 B
    __shared__ float kv[16][132];
    __shared__ float h6s[16][6];

    const int tid  = threadIdx.x;
    const int w    = tid >> 6;
    const int lane = tid & 63;
    const int quad = lane >> 4;
    const int l16  = lane & 15;
    const int b0   = blockIdx.x * 16;

    f32x4 acc[9];
    #pragma unroll
    for (int t = 0; t < 9; t++) acc[t] = (f32x4){0.f, 0.f, 0.f, 0.f};

    const float* xp = x + (size_t)(b0 + l16) * KCTRL + w * 256 + quad * 8;
    const unsigned short* wtp = Wt + (size_t)l16 * KCTRL + w * 256 + quad * 8;

    #pragma unroll
    for (int i = 0; i < 8; i++) {
        const int k0 = i * 32;
        const float4 xa = *(const float4*)(xp + k0);
        const float4 xb = *(const float4*)(xp + k0 + 4);
        bf16x8 af;
        af[0] = (short)f2bf(xa.x); af[1] = (short)f2bf(xa.y);
        af[2] = (short)f2bf(xa.z); af[3] = (short)f2bf(xa.w);
        af[4] = (short)f2bf(xb.x); af[5] = (short)f2bf(xb.y);
        af[6] = (short)f2bf(xb.z); af[7] = (short)f2bf(xb.w);
        #pragma unroll
        for (int t = 0; t < 9; t++) {
            const bf16x8 bf = *(const bf16x8*)(wtp + (size_t)t * 16 * KCTRL + k0);
            acc[t] = __builtin_amdgcn_mfma_f32_16x16x32_bf16(af, bf, acc[t], 0, 0, 0);
        }
    }
    #pragma unroll
    for (int t = 0; t < 9; t++) {
        #pragma unroll
        for (int reg = 0; reg < 4; reg++) {
            red[w][quad * 4 + reg][t * 16 + l16] = acc[t][reg];
        }
    }
    __syncthreads();

    #pragma unroll
    for (int e = 0; e < 9; e++) {
        const int f = tid + 256 * e;
        const int m = f / 144;
        const int c = f - m * 144;
        const float v = red[0][m][c] + red[1][m][c] + red[2][m][c] + red[3][m][c] + bfc[c];
        if (c < 128) {
            k_bf[(size_t)(b0 + m) * NC + c] = f2bf(v);
            kv[m][c] = v;
        } else if (c < 134) {
            h6s[m][c - 128] = v;
        }
    }
    __syncthreads();

    {
        const int m = tid >> 4;
        const int l = tid & 15;
        float s = 0.f;
        #pragma unroll
        for (int i = 0; i < 8; i++) {
            const float v = kv[m][l + 16 * i];
            s = fmaf(v, v, s);
        }
        #pragma unroll
        for (int ss = 1; ss < 16; ss <<= 1) s += __shfl_xor(s, ss);
        if (l == 0) {
            const float kn = sqrtf(s);
            const float* h = h6s[m];
            const float beta = softplus_f(h[0]);
            const float g = 1.f / (1.f + __expf(-h[1]));
            const float m3 = fmaxf(h[2], fmaxf(h[3], h[4]));
            const float e0 = __expf(h[2] - m3), e1 = __expf(h[3] - m3), e2 = __expf(h[4] - m3);
            const float inv = 1.f / (e0 + e1 + e2);
            const float gamma = 1.f + softplus_f(h[5]);
            float* sc = scal + (size_t)(b0 + m) * 8;
            sc[0] = beta / kn; sc[1] = g; sc[2] = e0 * inv; sc[3] = e1 * inv;
            sc[4] = e2 * inv; sc[5] = gamma; sc[6] = 0.f; sc[7] = 0.f;
        }
    }
}

// ---------------- K2: fused head (MFMA), 512 threads / 16 rows ----------------
__global__ __launch_bounds__(512) void head_mfma(const unsigned short* __restrict__ Mb,
                                                 const unsigned short* __restrict__ Mt,
                                                 const float* __restrict__ imn,
                                                 const unsigned short* __restrict__ k_bf,
                                                 const float* __restrict__ scal,
                                                 const float* __restrict__ wprev,
                                                 float* __restrict__ out) {
    __shared__ __align__(16) unsigned short E_s[16][ESTR];   // 65792 B
    __shared__ float scal_s[16][8];
    __shared__ float wred[16][8];
    __shared__ float fa_s[16], fc_s[16], invZ_s[16];

    const int tid  = threadIdx.x;
    const int w    = tid >> 6;         // 8 waves
    const int lane = tid & 63;
    const int quad = lane >> 4;
    const int l16  = lane & 15;
    const int b0   = blockIdx.x * 16;

    if (tid < 128) scal_s[tid >> 3][tid & 7] = scal[(size_t)(b0 + (tid >> 3)) * 8 + (tid & 7)];
    __syncthreads();

    // ---- phase 1: E = exp((beta/kn)*(1/mn)*(k . M_i)) ----
    float cbs[4];
    #pragma unroll
    for (int reg = 0; reg < 4; reg++) cbs[reg] = scal_s[quad * 4 + reg][0];

    const unsigned short* ap = k_bf + (size_t)(b0 + l16) * NC + quad * 8;
    const bf16x8 af0 = *(const bf16x8*)(ap);
    const bf16x8 af1 = *(const bf16x8*)(ap + 32);
    const bf16x8 af2 = *(const bf16x8*)(ap + 64);
    const bf16x8 af3 = *(const bf16x8*)(ap + 96);

    float Sp[4] = {0.f, 0.f, 0.f, 0.f};
    for (int t = 0; t < 16; t++) {
        const int n0 = w * 256 + t * 16;
        const unsigned short* bp = Mb + (size_t)(n0 + l16) * NC + quad * 8;
        f32x4 acc = {0.f, 0.f, 0.f, 0.f};
        acc = __builtin_amdgcn_mfma_f32_16x16x32_bf16(af0, *(const bf16x8*)(bp), acc, 0, 0, 0);
        acc = __builtin_amdgcn_mfma_f32_16x16x32_bf16(af1, *(const bf16x8*)(bp + 32), acc, 0, 0, 0);
        acc = __builtin_amdgcn_mfma_f32_16x16x32_bf16(af2, *(const bf16x8*)(bp + 64), acc, 0, 0, 0);
        acc = __builtin_amdgcn_mfma_f32_16x16x32_bf16(af3, *(const bf16x8*)(bp + 96), acc, 0, 0, 0);
        const float im = imn[n0 + l16];
        #pragma unroll
        for (int reg = 0; reg < 4; reg++) {
            const float e = __expf(acc[reg] * cbs[reg] * im);
            E_s[quad * 4 + reg][n0 + l16] = f2bf(e);
            Sp[reg] += e;
        }
    }
    #pragma unroll
    for (int s = 1; s < 16; s <<= 1) {
        #pragma unroll
        for (int reg = 0; reg < 4; reg++) Sp[reg] += __shfl_xor(Sp[reg], s);
    }
    if (l16 == 0) {
        #pragma unroll
        for (int reg = 0; reg < 4; reg++) wred[quad * 4 + reg][w] = Sp[reg];
    }
    __syncthreads();
    if (tid < 16) {
        float S = 0.f;
        #pragma unroll
        for (int i = 0; i < 8; i++) S += wred[tid][i];
        const float g = scal_s[tid][1];
        fa_s[tid] = g / S;
        fc_s[tid] = 1.f - g;
    }
    __syncthreads();

    // ---- phase 1.5: parallel shift+pow, in place ----
    // Row r owned by one 32-lane half-wave (lockstep). Lane g owns 8 chunks of
    // 8: cols [(g+32j)*8, +8). In-wave lockstep => all reads of iter j precede
    // all writes of iter j. Only two positions can be read after overwrite:
    // lane0's left edge (written at j-1) and lane31/j7's right wrap (written at
    // j=0) -> carried in registers via shfl.
    {
        const int row  = tid >> 5;
        const int g    = tid & 31;
        const int base = tid & 32;           // wave-local half base
        const float s0 = scal_s[row][2], s1 = scal_s[row][3], s2 = scal_s[row][4];
        const float gmm = scal_s[row][5];
        const float fa = fa_s[row], fcm = fc_s[row];
        const float* wp = wprev + (size_t)(b0 + row) * NR;

        float Zp = 0.f;
        float carry = 0.f, E0sav = 0.f;
        #pragma unroll
        for (int j = 0; j < 8; j++) {
            const int c0 = (g + 32 * j) * 8;
            const bf16x8 E8 = *(const bf16x8*)&E_s[row][c0];
            float ef[8];
            #pragma unroll
            for (int i = 0; i < 8; i++) ef[i] = bf2f((unsigned short)E8[i]);
            const float eLraw = bf2f(E_s[row][(c0 + NR - 1) & (NR - 1)]);
            const float eRraw = bf2f(E_s[row][(c0 + 8) & (NR - 1)]);
            if (j == 0) E0sav = __shfl(ef[0], base);
            const float eL = (g == 0 && j > 0) ? carry : eLraw;
            const float eR = (g == 31 && j == 7) ? E0sav : eRraw;
            carry = __shfl(ef[7], base + 31);

            const float4 wa = *(const float4*)(wp + c0);
            const float4 wb = *(const float4*)(wp + c0 + 4);
            const float wpL = wp[(c0 + NR - 1) & (NR - 1)];
            const float wpR = wp[(c0 + 8) & (NR - 1)];

            float wg[10];
            wg[0] = fmaf(fa, eL,    fcm * wpL);
            wg[1] = fmaf(fa, ef[0], fcm * wa.x);
            wg[2] = fmaf(fa, ef[1], fcm * wa.y);
            wg[3] = fmaf(fa, ef[2], fcm * wa.z);
            wg[4] = fmaf(fa, ef[3], fcm * wa.w);
            wg[5] = fmaf(fa, ef[4], fcm * wb.x);
            wg[6] = fmaf(fa, ef[5], fcm * wb.y);
            wg[7] = fmaf(fa, ef[6], fcm * wb.z);
            wg[8] = fmaf(fa, ef[7], fcm * wb.w);
            wg[9] = fmaf(fa, eR,    fcm * wpR);

            bf16x8 out8;
            #pragma unroll
            for (int i = 0; i < 8; i++) {
                const float wt = fmaf(s0, wg[i], fmaf(s1, wg[i + 1], s2 * wg[i + 2])) + EPSF;
                const float pw = __expf(gmm * __logf(wt));
                Zp += pw;
                out8[i] = (short)f2bf(pw);
            }
            *(bf16x8*)&E_s[row][c0] = out8;
        }
        #pragma unroll
        for (int s = 1; s < 32; s <<= 1) Zp += __shfl_xor(Zp, s);
        if (g == 0) invZ_s[row] = 1.f / Zp;
    }
    __syncthreads();

    // ---- phase 2: r = (w_pow @ M) * invZ  (wave w -> 16 output cols) ----
    {
        f32x4 accA = {0.f, 0.f, 0.f, 0.f};
        f32x4 accB = {0.f, 0.f, 0.f, 0.f};
        const unsigned short* bp = Mt + (size_t)(w * 16 + l16) * NR + quad * 8;
        for (int k0 = 0; k0 < NR; k0 += 64) {
            const bf16x8 a0 = *(const bf16x8*)&E_s[l16][k0 + quad * 8];
            const bf16x8 a1 = *(const bf16x8*)&E_s[l16][k0 + 32 + quad * 8];
            const bf16x8 b0v = *(const bf16x8*)(bp + k0);
            const bf16x8 b1v = *(const bf16x8*)(bp + k0 + 32);
            accA = __builtin_amdgcn_mfma_f32_16x16x32_bf16(a0, b0v, accA, 0, 0, 0);
            accB = __builtin_amdgcn_mfma_f32_16x16x32_bf16(a1, b1v, accB, 0, 0, 0);
        }
        #pragma unroll
        for (int reg = 0; reg < 4; reg++) {
            const int m = quad * 4 + reg;
            out[(size_t)(b0 + m) * NC + w * 16 + l16] = (accA[reg] + accB[reg]) * invZ_s[m];
        }
    }
}

extern "C" void kernel_launch(void* const* d_in, const int* in_sizes, int n_in,
                              void* d_out, int out_size, void* d_ws, size_t ws_size,
                              hipStream_t stream) {
    const float* x     = (const float*)d_in[0];
    const float* Wfc   = (const float*)d_in[1];
    const float* bfc   = (const float*)d_in[2];
    const float* M     = (const float*)d_in[3];
    const float* wprev = (const float*)d_in[4];
    float* out = (float*)d_out;

    char* ws = (char*)d_ws;
    unsigned short* k_bf = (unsigned short*)(ws);              // 4194304 B
    float*          scal = (float*)(ws + 4194304);             // 524288 B
    float*          imn  = (float*)(ws + 4718592);             // 8192 B
    unsigned short* Mb   = (unsigned short*)(ws + 4726784);    // 524288 B
    unsigned short* Mt   = (unsigned short*)(ws + 5251072);    // 524288 B
    unsigned short* Wt   = (unsigned short*)(ws + 5775360);    // 294912 B

    hipLaunchKernelGGL(prep_m, dim3(NR), dim3(64), 0, stream, M, Mb, Mt, imn);
    hipLaunchKernelGGL(prep_w, dim3(KCTRL), dim3(64), 0, stream, Wfc, Wt);
    hipLaunchKernelGGL(fc_mfma, dim3(NB / 16), dim3(256), 0, stream, x, Wt, bfc, k_bf, scal);
    hipLaunchKernelGGL(head_mfma, dim3(NB / 16), dim3(512), 0, stream,
                       Mb, Mt, imn, k_bf, scal, wprev, out);
}

// Round 5
// 386.473 us; speedup vs baseline: 3.5170x; 1.0033x over previous
//
#include <hip/hip_runtime.h>
#include <hip/hip_bf16.h>

#define NB    16384   // batch
#define NR    2048    // memory rows
#define NC    128     // memory cols (= key dim)
#define KCTRL 1024    // controller dim
#define EPSF  1e-16f
#define ESTR  2056    // E_s row stride (bf16): 2048 + 8 -> 4112 B, 16B-aligned

typedef __attribute__((ext_vector_type(8))) short bf16x8;
typedef __attribute__((ext_vector_type(4))) float f32x4;

__device__ __forceinline__ float softplus_f(float x) {
    return fmaxf(x, 0.f) + log1pf(__expf(-fabsf(x)));
}
__device__ __forceinline__ unsigned short f2bf(float f) {
    __hip_bfloat16 h = __float2bfloat16(f);
    return *(unsigned short*)&h;
}
__device__ __forceinline__ float bf2f(unsigned short u) {
    __hip_bfloat16 h;
    *(unsigned short*)&h = u;
    return __bfloat162float(h);
}

// ---------------- P: merged prep (blocks 0..2047: M; 2048..3071: W) ----------
__global__ __launch_bounds__(64) void prep_all(const float* __restrict__ M,
                                               unsigned short* __restrict__ Mb,
                                               unsigned short* __restrict__ Mt,
                                               float* __restrict__ imn,
                                               const float* __restrict__ W,
                                               unsigned short* __restrict__ Wt) {
    const int bid = blockIdx.x;
    const int l = threadIdx.x;
    if (bid < NR) {
        const int i = bid;
        const float v0 = M[(size_t)i * NC + l];
        const float v1 = M[(size_t)i * NC + 64 + l];
        Mb[(size_t)i * NC + l]      = f2bf(v0);
        Mb[(size_t)i * NC + 64 + l] = f2bf(v1);
        Mt[(size_t)l * NR + i]        = f2bf(v0);
        Mt[(size_t)(64 + l) * NR + i] = f2bf(v1);
        float s = v0 * v0 + v1 * v1;
        #pragma unroll
        for (int m = 1; m < 64; m <<= 1) s += __shfl_xor(s, m);
        if (l == 0) imn[i] = 1.f / sqrtf(s);
    } else {
        const int k = bid - NR;   // 0..1023
        const float a = W[(size_t)k * 134 + l];
        const float b = W[(size_t)k * 134 + 64 + l];
        Wt[(size_t)l * KCTRL + k]        = f2bf(a);
        Wt[(size_t)(64 + l) * KCTRL + k] = f2bf(b);
        if (l < 6) {
            const float c = W[(size_t)k * 134 + 128 + l];
            Wt[(size_t)(128 + l) * KCTRL + k] = f2bf(c);
        }
    }
}

// ---------------- K1: h = x @ W_fc + b_fc via MFMA ----------------
// 16 batch rows / block, 256 threads. Wave w owns K in [w*256,(w+1)*256).
// A-frags (x slice) converted ONCE into 32 VGPRs; then 9 column tiles are
// processed serially with a single live accumulator (low VGPR, no spill).
// Cross-wave K-reduce in LDS; epilogue: k_bf16, knorm, per-row scalars.
// scal[b][8] = {beta/knorm, g, s0, s1, s2, gamma, -, -}
__global__ __launch_bounds__(256, 3) void fc_mfma(const float* __restrict__ x,
                                                  const unsigned short* __restrict__ Wt,
                                                  const float* __restrict__ bfc,
                                                  unsigned short* __restrict__ k_bf,
                                                  float* __restrict__ scal) {
    __shared__ float red[4][16][148];   // 37888 B
    __shared__ float kv[16][132];
    __shared__ float h6s[16][6];

    const int tid  = threadIdx.x;
    const int w    = tid >> 6;
    const int lane = tid & 63;
    const int quad = lane >> 4;
    const int l16  = lane & 15;
    const int b0   = blockIdx.x * 16;

    // load + convert the 8 A-frags once (32 VGPRs)
    bf16x8 A[8];
    {
        const float* xp = x + (size_t)(b0 + l16) * KCTRL + w * 256 + quad * 8;
        #pragma unroll
        for (int i = 0; i < 8; i++) {
            const float4 xa = *(const float4*)(xp + i * 32);
            const float4 xb = *(const float4*)(xp + i * 32 + 4);
            bf16x8 af;
            af[0] = (short)f2bf(xa.x); af[1] = (short)f2bf(xa.y);
            af[2] = (short)f2bf(xa.z); af[3] = (short)f2bf(xa.w);
            af[4] = (short)f2bf(xb.x); af[5] = (short)f2bf(xb.y);
            af[6] = (short)f2bf(xb.z); af[7] = (short)f2bf(xb.w);
            A[i] = af;
        }
    }

    // 9 column tiles, one accumulator at a time
    #pragma unroll
    for (int t = 0; t < 9; t++) {
        const unsigned short* wtp = Wt + (size_t)(t * 16 + l16) * KCTRL + w * 256 + quad * 8;
        f32x4 acc = {0.f, 0.f, 0.f, 0.f};
        #pragma unroll
        for (int i = 0; i < 8; i++) {
            const bf16x8 bf = *(const bf16x8*)(wtp + i * 32);
            acc = __builtin_amdgcn_mfma_f32_16x16x32_bf16(A[i], bf, acc, 0, 0, 0);
        }
        #pragma unroll
        for (int reg = 0; reg < 4; reg++) {
            red[w][quad * 4 + reg][t * 16 + l16] = acc[reg];
        }
    }
    __syncthreads();

    #pragma unroll
    for (int e = 0; e < 9; e++) {
        const int f = tid + 256 * e;
        const int m = f / 144;
        const int c = f - m * 144;
        const float v = red[0][m][c] + red[1][m][c] + red[2][m][c] + red[3][m][c] + bfc[c];
        if (c < 128) {
            k_bf[(size_t)(b0 + m) * NC + c] = f2bf(v);
            kv[m][c] = v;
        } else if (c < 134) {
            h6s[m][c - 128] = v;
        }
    }
    __syncthreads();

    {
        const int m = tid >> 4;
        const int l = tid & 15;
        float s = 0.f;
        #pragma unroll
        for (int i = 0; i < 8; i++) {
            const float v = kv[m][l + 16 * i];
            s = fmaf(v, v, s);
        }
        #pragma unroll
        for (int ss = 1; ss < 16; ss <<= 1) s += __shfl_xor(s, ss);
        if (l == 0) {
            const float kn = sqrtf(s);
            const float* h = h6s[m];
            const float beta = softplus_f(h[0]);
            const float g = 1.f / (1.f + __expf(-h[1]));
            const float m3 = fmaxf(h[2], fmaxf(h[3], h[4]));
            const float e0 = __expf(h[2] - m3), e1 = __expf(h[3] - m3), e2 = __expf(h[4] - m3);
            const float inv = 1.f / (e0 + e1 + e2);
            const float gamma = 1.f + softplus_f(h[5]);
            float* sc = scal + (size_t)(b0 + m) * 8;
            sc[0] = beta / kn; sc[1] = g; sc[2] = e0 * inv; sc[3] = e1 * inv;
            sc[4] = e2 * inv; sc[5] = gamma; sc[6] = 0.f; sc[7] = 0.f;
        }
    }
}

// ---------------- K2: fused head (MFMA), 512 threads / 16 rows ----------------
__global__ __launch_bounds__(512, 4) void head_mfma(const unsigned short* __restrict__ Mb,
                                                    const unsigned short* __restrict__ Mt,
                                                    const float* __restrict__ imn,
                                                    const unsigned short* __restrict__ k_bf,
                                                    const float* __restrict__ scal,
                                                    const float* __restrict__ wprev,
                                                    float* __restrict__ out) {
    __shared__ __align__(16) unsigned short E_s[16][ESTR];   // 65792 B
    __shared__ float scal_s[16][8];
    __shared__ float wred[16][8];
    __shared__ float fa_s[16], fc_s[16], invZ_s[16];

    const int tid  = threadIdx.x;
    const int w    = tid >> 6;         // 8 waves
    const int lane = tid & 63;
    const int quad = lane >> 4;
    const int l16  = lane & 15;
    const int b0   = blockIdx.x * 16;

    if (tid < 128) scal_s[tid >> 3][tid & 7] = scal[(size_t)(b0 + (tid >> 3)) * 8 + (tid & 7)];
    __syncthreads();

    // ---- phase 1: E = exp((beta/kn)*(1/mn)*(k . M_i)), two MFMA chains ----
    float cbs[4];
    #pragma unroll
    for (int reg = 0; reg < 4; reg++) cbs[reg] = scal_s[quad * 4 + reg][0];

    const unsigned short* ap = k_bf + (size_t)(b0 + l16) * NC + quad * 8;
    const bf16x8 af0 = *(const bf16x8*)(ap);
    const bf16x8 af1 = *(const bf16x8*)(ap + 32);
    const bf16x8 af2 = *(const bf16x8*)(ap + 64);
    const bf16x8 af3 = *(const bf16x8*)(ap + 96);

    float Sp[4] = {0.f, 0.f, 0.f, 0.f};
    #pragma unroll 4
    for (int t = 0; t < 16; t++) {
        const int n0 = w * 256 + t * 16;
        const unsigned short* bp = Mb + (size_t)(n0 + l16) * NC + quad * 8;
        f32x4 aA = {0.f, 0.f, 0.f, 0.f};
        f32x4 aB = {0.f, 0.f, 0.f, 0.f};
        aA = __builtin_amdgcn_mfma_f32_16x16x32_bf16(af0, *(const bf16x8*)(bp), aA, 0, 0, 0);
        aB = __builtin_amdgcn_mfma_f32_16x16x32_bf16(af2, *(const bf16x8*)(bp + 64), aB, 0, 0, 0);
        aA = __builtin_amdgcn_mfma_f32_16x16x32_bf16(af1, *(const bf16x8*)(bp + 32), aA, 0, 0, 0);
        aB = __builtin_amdgcn_mfma_f32_16x16x32_bf16(af3, *(const bf16x8*)(bp + 96), aB, 0, 0, 0);
        const float im = imn[n0 + l16];
        #pragma unroll
        for (int reg = 0; reg < 4; reg++) {
            const float e = __expf((aA[reg] + aB[reg]) * cbs[reg] * im);
            E_s[quad * 4 + reg][n0 + l16] = f2bf(e);
            Sp[reg] += e;
        }
    }
    #pragma unroll
    for (int s = 1; s < 16; s <<= 1) {
        #pragma unroll
        for (int reg = 0; reg < 4; reg++) Sp[reg] += __shfl_xor(Sp[reg], s);
    }
    if (l16 == 0) {
        #pragma unroll
        for (int reg = 0; reg < 4; reg++) wred[quad * 4 + reg][w] = Sp[reg];
    }
    __syncthreads();
    if (tid < 16) {
        float S = 0.f;
        #pragma unroll
        for (int i = 0; i < 8; i++) S += wred[tid][i];
        const float g = scal_s[tid][1];
        fa_s[tid] = g / S;
        fc_s[tid] = 1.f - g;
    }
    __syncthreads();

    // ---- phase 1.5: parallel shift+pow, in place ----
    // Row r owned by one 32-lane half-wave (lockstep). Lane g owns 8 chunks of
    // 8: cols [(g+32j)*8, +8). In-wave lockstep => all reads of iter j precede
    // all writes of iter j. Only two positions can be read after overwrite:
    // lane0's left edge (written at j-1) and lane31/j7's right wrap (written at
    // j=0) -> carried in registers via shfl.
    {
        const int row  = tid >> 5;
        const int g    = tid & 31;
        const int base = tid & 32;           // wave-local half base
        const float s0 = scal_s[row][2], s1 = scal_s[row][3], s2 = scal_s[row][4];
        const float gmm = scal_s[row][5];
        const float fa = fa_s[row], fcm = fc_s[row];
        const float* wp = wprev + (size_t)(b0 + row) * NR;

        float Zp = 0.f;
        float carry = 0.f, E0sav = 0.f;
        #pragma unroll
        for (int j = 0; j < 8; j++) {
            const int c0 = (g + 32 * j) * 8;
            const bf16x8 E8 = *(const bf16x8*)&E_s[row][c0];
            float ef[8];
            #pragma unroll
            for (int i = 0; i < 8; i++) ef[i] = bf2f((unsigned short)E8[i]);
            const float eLraw = bf2f(E_s[row][(c0 + NR - 1) & (NR - 1)]);
            const float eRraw = bf2f(E_s[row][(c0 + 8) & (NR - 1)]);
            if (j == 0) E0sav = __shfl(ef[0], base);
            const float eL = (g == 0 && j > 0) ? carry : eLraw;
            const float eR = (g == 31 && j == 7) ? E0sav : eRraw;
            carry = __shfl(ef[7], base + 31);

            const float4 wa = *(const float4*)(wp + c0);
            const float4 wb = *(const float4*)(wp + c0 + 4);
            const float wpL = wp[(c0 + NR - 1) & (NR - 1)];
            const float wpR = wp[(c0 + 8) & (NR - 1)];

            float wg[10];
            wg[0] = fmaf(fa, eL,    fcm * wpL);
            wg[1] = fmaf(fa, ef[0], fcm * wa.x);
            wg[2] = fmaf(fa, ef[1], fcm * wa.y);
            wg[3] = fmaf(fa, ef[2], fcm * wa.z);
            wg[4] = fmaf(fa, ef[3], fcm * wa.w);
            wg[5] = fmaf(fa, ef[4], fcm * wb.x);
            wg[6] = fmaf(fa, ef[5], fcm * wb.y);
            wg[7] = fmaf(fa, ef[6], fcm * wb.z);
            wg[8] = fmaf(fa, ef[7], fcm * wb.w);
            wg[9] = fmaf(fa, eR,    fcm * wpR);

            bf16x8 out8;
            #pragma unroll
            for (int i = 0; i < 8; i++) {
                const float wt = fmaf(s0, wg[i], fmaf(s1, wg[i + 1], s2 * wg[i + 2])) + EPSF;
                const float pw = __expf(gmm * __logf(wt));
                Zp += pw;
                out8[i] = (short)f2bf(pw);
            }
            *(bf16x8*)&E_s[row][c0] = out8;
        }
        #pragma unroll
        for (int s = 1; s < 32; s <<= 1) Zp += __shfl_xor(Zp, s);
        if (g == 0) invZ_s[row] = 1.f / Zp;
    }
    __syncthreads();

    // ---- phase 2: r = (w_pow @ M) * invZ, 4 independent MFMA chains ----
    {
        f32x4 acc0 = {0.f, 0.f, 0.f, 0.f};
        f32x4 acc1 = {0.f, 0.f, 0.f, 0.f};
        f32x4 acc2 = {0.f, 0.f, 0.f, 0.f};
        f32x4 acc3 = {0.f, 0.f, 0.f, 0.f};
        const unsigned short* bp = Mt + (size_t)(w * 16 + l16) * NR + quad * 8;
        for (int k0 = 0; k0 < NR; k0 += 128) {
            const bf16x8 a0 = *(const bf16x8*)&E_s[l16][k0 + quad * 8];
            const bf16x8 a1 = *(const bf16x8*)&E_s[l16][k0 + 32 + quad * 8];
            const bf16x8 a2 = *(const bf16x8*)&E_s[l16][k0 + 64 + quad * 8];
            const bf16x8 a3 = *(const bf16x8*)&E_s[l16][k0 + 96 + quad * 8];
            const bf16x8 b0v = *(const bf16x8*)(bp + k0);
            const bf16x8 b1v = *(const bf16x8*)(bp + k0 + 32);
            const bf16x8 b2v = *(const bf16x8*)(bp + k0 + 64);
            const bf16x8 b3v = *(const bf16x8*)(bp + k0 + 96);
            acc0 = __builtin_amdgcn_mfma_f32_16x16x32_bf16(a0, b0v, acc0, 0, 0, 0);
            acc1 = __builtin_amdgcn_mfma_f32_16x16x32_bf16(a1, b1v, acc1, 0, 0, 0);
            acc2 = __builtin_amdgcn_mfma_f32_16x16x32_bf16(a2, b2v, acc2, 0, 0, 0);
            acc3 = __builtin_amdgcn_mfma_f32_16x16x32_bf16(a3, b3v, acc3, 0, 0, 0);
        }
        #pragma unroll
        for (int reg = 0; reg < 4; reg++) {
            const int m = quad * 4 + reg;
            const float v = (acc0[reg] + acc1[reg]) + (acc2[reg] + acc3[reg]);
            out[(size_t)(b0 + m) * NC + w * 16 + l16] = v * invZ_s[m];
        }
    }
}

extern "C" void kernel_launch(void* const* d_in, const int* in_sizes, int n_in,
                              void* d_out, int out_size, void* d_ws, size_t ws_size,
                              hipStream_t stream) {
    const float* x     = (const float*)d_in[0];
    const float* Wfc   = (const float*)d_in[1];
    const float* bfc   = (const float*)d_in[2];
    const float* M     = (const float*)d_in[3];
    const float* wprev = (const float*)d_in[4];
    float* out = (float*)d_out;

    char* ws = (char*)d_ws;
    unsigned short* k_bf = (unsigned short*)(ws);              // 4194304 B
    float*          scal = (float*)(ws + 4194304);             // 524288 B
    float*          imn  = (float*)(ws + 4718592);             // 8192 B
    unsigned short* Mb   = (unsigned short*)(ws + 4726784);    // 524288 B
    unsigned short* Mt   = (unsigned short*)(ws + 5251072);    // 524288 B
    unsigned short* Wt   = (unsigned short*)(ws + 5775360);    // 294912 B

    hipLaunchKernelGGL(prep_all, dim3(NR + KCTRL), dim3(64), 0, stream, M, Mb, Mt, imn, Wfc, Wt);
    hipLaunchKernelGGL(fc_mfma, dim3(NB / 16), dim3(256), 0, stream, x, Wt, bfc, k_bf, scal);
    hipLaunchKernelGGL(head_mfma, dim3(NB / 16), dim3(512), 0, stream,
                       Mb, Mt, imn, k_bf, scal, wprev, out);
}

// Round 6
// 303.761 us; speedup vs baseline: 4.4747x; 1.2723x over previous
//
#include <hip/hip_runtime.h>
#include <hip/hip_bf16.h>

#define NB    16384   // batch
#define NR    2048    // memory rows
#define NC    128     // memory cols (= key dim)
#define KCTRL 1024    // controller dim
#define EPSF  1e-16f
#define ESTR  2056    // E_s row stride (bf16)
#define XSTR  1032    // fc x-stage row stride (bf16)

typedef __attribute__((ext_vector_type(8))) short bf16x8;
typedef __attribute__((ext_vector_type(4))) float f32x4;

__device__ __forceinline__ float softplus_f(float x) {
    return fmaxf(x, 0.f) + log1pf(__expf(-fabsf(x)));
}
__device__ __forceinline__ unsigned short f2bf(float f) {
    __hip_bfloat16 h = __float2bfloat16(f);
    return *(unsigned short*)&h;
}
__device__ __forceinline__ float bf2f(unsigned short u) {
    __hip_bfloat16 h;
    *(unsigned short*)&h = u;
    return __bfloat162float(h);
}

// Fragment-order swizzle: element (row n, col k) of an operand matrix, tiled
// 16 rows x 32 cols, stored so one wave's 16x32 fragment is 64 lanes x 8 bf16
// contiguous (1 KB). idx = ((tile*nch + chunk)*64 + quad*16 + l16)*8 + j.
__device__ __forceinline__ size_t swz(int n, int k, int nch) {
    return ((size_t)((n >> 4) * nch + (k >> 5)) * 64 + ((k >> 3) & 3) * 16 + (n & 15)) * 8 + (k & 7);
}

// ---------------- P: merged prep (blocks 0..2047: M; 2048..3071: W) ----------
__global__ __launch_bounds__(64) void prep_all(const float* __restrict__ M,
                                               unsigned short* __restrict__ Mb_sw,
                                               unsigned short* __restrict__ Mt_sw,
                                               float* __restrict__ imn,
                                               const float* __restrict__ W,
                                               unsigned short* __restrict__ Wt_sw) {
    const int bid = blockIdx.x;
    const int l = threadIdx.x;
    if (bid < NR) {
        const int i = bid;
        const float v0 = M[(size_t)i * NC + l];
        const float v1 = M[(size_t)i * NC + 64 + l];
        // Mb_sw: B-operand of sim (rows = memory rows, K = NC=128, 4 chunks)
        Mb_sw[swz(i, l, 4)]      = f2bf(v0);
        Mb_sw[swz(i, 64 + l, 4)] = f2bf(v1);
        // Mt_sw: B-operand of r (rows = M cols 0..127, K = NR=2048, 64 chunks)
        Mt_sw[swz(l, i, 64)]      = f2bf(v0);
        Mt_sw[swz(64 + l, i, 64)] = f2bf(v1);
        float s = v0 * v0 + v1 * v1;
        #pragma unroll
        for (int m = 1; m < 64; m <<= 1) s += __shfl_xor(s, m);
        if (l == 0) imn[i] = 1.f / sqrtf(s);
    } else {
        const int k = bid - NR;   // 0..1023
        // Wt_sw: B-operand of h (rows = head cols 0..143, K = 1024, 32 chunks)
        Wt_sw[swz(l, k, 32)]      = f2bf(W[(size_t)k * 134 + l]);
        Wt_sw[swz(64 + l, k, 32)] = f2bf(W[(size_t)k * 134 + 64 + l]);
        if (l < 6) {
            Wt_sw[swz(128 + l, k, 32)] = f2bf(W[(size_t)k * 134 + 128 + l]);
        }
    }
}

// ---------------- K1: h = x @ W_fc + b_fc via MFMA ----------------
// 16 batch rows / block, 256 threads, wave w owns K range [w*256,(w+1)*256).
// x tile staged coalesced -> LDS bf16; A-frags via ds_read_b128; B (Wt_sw)
// loads are coalesced 1-KB frag streams. x_s overlays the reduce scratch
// (barrier between). Epilogue: k in swizzled A-layout, knorm, scalars.
// scal[b][8] = {beta/knorm, g, s0, s1, s2, gamma, -, -}
__global__ __launch_bounds__(256, 3) void fc_mfma(const float* __restrict__ x,
                                                  const unsigned short* __restrict__ Wt_sw,
                                                  const float* __restrict__ bfc,
                                                  unsigned short* __restrict__ k_sw,
                                                  float* __restrict__ scal) {
    __shared__ __align__(16) char smem[4 * 16 * 148 * 4];   // 37888 B (red / x_s overlay)
    __shared__ float kv[16][132];
    __shared__ float h6s[16][6];

    unsigned short (*x_s)[XSTR] = (unsigned short(*)[XSTR])smem;  // 16*1032*2 = 33024 B
    float (*red)[16][148] = (float(*)[16][148])smem;

    const int tid  = threadIdx.x;
    const int w    = tid >> 6;
    const int lane = tid & 63;
    const int quad = lane >> 4;
    const int l16  = lane & 15;
    const int b0   = blockIdx.x * 16;

    // stage x tile: 16 rows x 1024 f32, coalesced read, bf16 to LDS
    #pragma unroll
    for (int p = 0; p < 16; p++) {
        const int idx = p * 256 + tid;          // float4 index
        const int row = idx >> 8;
        const int c4  = idx & 255;
        const float4 v = *(const float4*)(x + (size_t)(b0 + row) * KCTRL + c4 * 4);
        unsigned short* d = &x_s[row][c4 * 4];
        d[0] = f2bf(v.x); d[1] = f2bf(v.y); d[2] = f2bf(v.z); d[3] = f2bf(v.w);
    }
    __syncthreads();

    // A-frags from LDS (reused across all 9 tiles)
    bf16x8 A[8];
    #pragma unroll
    for (int i = 0; i < 8; i++) {
        A[i] = *(const bf16x8*)&x_s[l16][w * 256 + i * 32 + quad * 8];
    }

    // 9 column tiles, coalesced B streams
    f32x4 acc[9];
    #pragma unroll
    for (int t = 0; t < 9; t++) acc[t] = (f32x4){0.f, 0.f, 0.f, 0.f};
    const unsigned short* wb = Wt_sw + (size_t)(w * 8) * 512 + lane * 8;
    #pragma unroll
    for (int t = 0; t < 9; t++) {
        const unsigned short* wt = wb + (size_t)t * 32 * 512;
        #pragma unroll
        for (int i = 0; i < 8; i++) {
            const bf16x8 bf = *(const bf16x8*)(wt + i * 512);
            acc[t] = __builtin_amdgcn_mfma_f32_16x16x32_bf16(A[i], bf, acc[t], 0, 0, 0);
        }
    }
    __syncthreads();           // all x_s reads done; safe to overlay with red

    #pragma unroll
    for (int t = 0; t < 9; t++) {
        #pragma unroll
        for (int reg = 0; reg < 4; reg++) {
            red[w][quad * 4 + reg][t * 16 + l16] = acc[t][reg];
        }
    }
    __syncthreads();

    #pragma unroll
    for (int e = 0; e < 9; e++) {
        const int f = tid + 256 * e;
        const int m = f / 144;
        const int c = f - m * 144;
        const float v = red[0][m][c] + red[1][m][c] + red[2][m][c] + red[3][m][c] + bfc[c];
        if (c < 128) {
            k_sw[(size_t)(b0 >> 4) * 2048 + swz(m, c, 4)] = f2bf(v);
            kv[m][c] = v;
        } else if (c < 134) {
            h6s[m][c - 128] = v;
        }
    }
    __syncthreads();

    {
        const int m = tid >> 4;
        const int l = tid & 15;
        float s = 0.f;
        #pragma unroll
        for (int i = 0; i < 8; i++) {
            const float v = kv[m][l + 16 * i];
            s = fmaf(v, v, s);
        }
        #pragma unroll
        for (int ss = 1; ss < 16; ss <<= 1) s += __shfl_xor(s, ss);
        if (l == 0) {
            const float kn = sqrtf(s);
            const float* h = h6s[m];
            const float beta = softplus_f(h[0]);
            const float g = 1.f / (1.f + __expf(-h[1]));
            const float m3 = fmaxf(h[2], fmaxf(h[3], h[4]));
            const float e0 = __expf(h[2] - m3), e1 = __expf(h[3] - m3), e2 = __expf(h[4] - m3);
            const float inv = 1.f / (e0 + e1 + e2);
            const float gamma = 1.f + softplus_f(h[5]);
            float* sc = scal + (size_t)(b0 + m) * 8;
            sc[0] = beta / kn; sc[1] = g; sc[2] = e0 * inv; sc[3] = e1 * inv;
            sc[4] = e2 * inv; sc[5] = gamma; sc[6] = 0.f; sc[7] = 0.f;
        }
    }
}

// ---------------- K2: fused head (MFMA), 512 threads / 16 rows ----------------
__global__ __launch_bounds__(512, 4) void head_mfma(const unsigned short* __restrict__ Mb_sw,
                                                    const unsigned short* __restrict__ Mt_sw,
                                                    const float* __restrict__ imn,
                                                    const unsigned short* __restrict__ k_sw,
                                                    const float* __restrict__ scal,
                                                    const float* __restrict__ wprev,
                                                    float* __restrict__ out) {
    __shared__ __align__(16) unsigned short E_s[16][ESTR];   // 65792 B
    __shared__ float scal_s[16][8];
    __shared__ float wred[16][8];
    __shared__ float fa_s[16], fc_s[16], invZ_s[16];

    const int tid  = threadIdx.x;
    const int w    = tid >> 6;         // 8 waves
    const int lane = tid & 63;
    const int quad = lane >> 4;
    const int l16  = lane & 15;
    const int b0   = blockIdx.x * 16;

    if (tid < 128) scal_s[tid >> 3][tid & 7] = scal[(size_t)(b0 + (tid >> 3)) * 8 + (tid & 7)];
    __syncthreads();

    // ---- phase 1: E = exp((beta/kn)*(1/mn)*(k . M_i)), coalesced frags ----
    float cbs[4];
    #pragma unroll
    for (int reg = 0; reg < 4; reg++) cbs[reg] = scal_s[quad * 4 + reg][0];

    const unsigned short* ks = k_sw + (size_t)blockIdx.x * 2048 + lane * 8;
    const bf16x8 af0 = *(const bf16x8*)(ks);
    const bf16x8 af1 = *(const bf16x8*)(ks + 512);
    const bf16x8 af2 = *(const bf16x8*)(ks + 1024);
    const bf16x8 af3 = *(const bf16x8*)(ks + 1536);

    float Sp[4] = {0.f, 0.f, 0.f, 0.f};
    #pragma unroll 4
    for (int t = 0; t < 16; t++) {
        const int nt = w * 16 + t;
        const unsigned short* bp = Mb_sw + (size_t)nt * 2048 + lane * 8;
        f32x4 aA = {0.f, 0.f, 0.f, 0.f};
        f32x4 aB = {0.f, 0.f, 0.f, 0.f};
        aA = __builtin_amdgcn_mfma_f32_16x16x32_bf16(af0, *(const bf16x8*)(bp), aA, 0, 0, 0);
        aB = __builtin_amdgcn_mfma_f32_16x16x32_bf16(af2, *(const bf16x8*)(bp + 1024), aB, 0, 0, 0);
        aA = __builtin_amdgcn_mfma_f32_16x16x32_bf16(af1, *(const bf16x8*)(bp + 512), aA, 0, 0, 0);
        aB = __builtin_amdgcn_mfma_f32_16x16x32_bf16(af3, *(const bf16x8*)(bp + 1536), aB, 0, 0, 0);
        const int n0 = nt * 16;
        const float im = imn[n0 + l16];
        #pragma unroll
        for (int reg = 0; reg < 4; reg++) {
            const float e = __expf((aA[reg] + aB[reg]) * cbs[reg] * im);
            E_s[quad * 4 + reg][n0 + l16] = f2bf(e);
            Sp[reg] += e;
        }
    }
    #pragma unroll
    for (int s = 1; s < 16; s <<= 1) {
        #pragma unroll
        for (int reg = 0; reg < 4; reg++) Sp[reg] += __shfl_xor(Sp[reg], s);
    }
    if (l16 == 0) {
        #pragma unroll
        for (int reg = 0; reg < 4; reg++) wred[quad * 4 + reg][w] = Sp[reg];
    }
    __syncthreads();
    if (tid < 16) {
        float S = 0.f;
        #pragma unroll
        for (int i = 0; i < 8; i++) S += wred[tid][i];
        const float g = scal_s[tid][1];
        fa_s[tid] = g / S;
        fc_s[tid] = 1.f - g;
    }
    __syncthreads();

    // ---- phase 1.5: parallel shift+pow, in place (see R4 comments) ----
    {
        const int row  = tid >> 5;
        const int g    = tid & 31;
        const int base = tid & 32;           // wave-local half base
        const float s0 = scal_s[row][2], s1 = scal_s[row][3], s2 = scal_s[row][4];
        const float gmm = scal_s[row][5];
        const float fa = fa_s[row], fcm = fc_s[row];
        const float* wp = wprev + (size_t)(b0 + row) * NR;

        float Zp = 0.f;
        float carry = 0.f, E0sav = 0.f;
        #pragma unroll
        for (int j = 0; j < 8; j++) {
            const int c0 = (g + 32 * j) * 8;
            const bf16x8 E8 = *(const bf16x8*)&E_s[row][c0];
            float ef[8];
            #pragma unroll
            for (int i = 0; i < 8; i++) ef[i] = bf2f((unsigned short)E8[i]);
            const float eLraw = bf2f(E_s[row][(c0 + NR - 1) & (NR - 1)]);
            const float eRraw = bf2f(E_s[row][(c0 + 8) & (NR - 1)]);
            if (j == 0) E0sav = __shfl(ef[0], base);
            const float eL = (g == 0 && j > 0) ? carry : eLraw;
            const float eR = (g == 31 && j == 7) ? E0sav : eRraw;
            carry = __shfl(ef[7], base + 31);

            const float4 wa = *(const float4*)(wp + c0);
            const float4 wb = *(const float4*)(wp + c0 + 4);
            const float wpL = wp[(c0 + NR - 1) & (NR - 1)];
            const float wpR = wp[(c0 + 8) & (NR - 1)];

            float wg[10];
            wg[0] = fmaf(fa, eL,    fcm * wpL);
            wg[1] = fmaf(fa, ef[0], fcm * wa.x);
            wg[2] = fmaf(fa, ef[1], fcm * wa.y);
            wg[3] = fmaf(fa, ef[2], fcm * wa.z);
            wg[4] = fmaf(fa, ef[3], fcm * wa.w);
            wg[5] = fmaf(fa, ef[4], fcm * wb.x);
            wg[6] = fmaf(fa, ef[5], fcm * wb.y);
            wg[7] = fmaf(fa, ef[6], fcm * wb.z);
            wg[8] = fmaf(fa, ef[7], fcm * wb.w);
            wg[9] = fmaf(fa, eR,    fcm * wpR);

            bf16x8 out8;
            #pragma unroll
            for (int i = 0; i < 8; i++) {
                const float wt = fmaf(s0, wg[i], fmaf(s1, wg[i + 1], s2 * wg[i + 2])) + EPSF;
                const float pw = __expf(gmm * __logf(wt));
                Zp += pw;
                out8[i] = (short)f2bf(pw);
            }
            *(bf16x8*)&E_s[row][c0] = out8;
        }
        #pragma unroll
        for (int s = 1; s < 32; s <<= 1) Zp += __shfl_xor(Zp, s);
        if (g == 0) invZ_s[row] = 1.f / Zp;
    }
    __syncthreads();

    // ---- phase 2: r = (w_pow @ M) * invZ, coalesced Mt_sw frags ----
    {
        f32x4 acc0 = {0.f, 0.f, 0.f, 0.f};
        f32x4 acc1 = {0.f, 0.f, 0.f, 0.f};
        f32x4 acc2 = {0.f, 0.f, 0.f, 0.f};
        f32x4 acc3 = {0.f, 0.f, 0.f, 0.f};
        const unsigned short* bp = Mt_sw + (size_t)w * 32768 + lane * 8;
        for (int k0 = 0; k0 < NR; k0 += 128) {
            const int C = k0 >> 5;
            const bf16x8 a0 = *(const bf16x8*)&E_s[l16][k0 + quad * 8];
            const bf16x8 a1 = *(const bf16x8*)&E_s[l16][k0 + 32 + quad * 8];
            const bf16x8 a2 = *(const bf16x8*)&E_s[l16][k0 + 64 + quad * 8];
            const bf16x8 a3 = *(const bf16x8*)&E_s[l16][k0 + 96 + quad * 8];
            const bf16x8 b0v = *(const bf16x8*)(bp + (size_t)C * 512);
            const bf16x8 b1v = *(const bf16x8*)(bp + (size_t)(C + 1) * 512);
            const bf16x8 b2v = *(const bf16x8*)(bp + (size_t)(C + 2) * 512);
            const bf16x8 b3v = *(const bf16x8*)(bp + (size_t)(C + 3) * 512);
            acc0 = __builtin_amdgcn_mfma_f32_16x16x32_bf16(a0, b0v, acc0, 0, 0, 0);
            acc1 = __builtin_amdgcn_mfma_f32_16x16x32_bf16(a1, b1v, acc1, 0, 0, 0);
            acc2 = __builtin_amdgcn_mfma_f32_16x16x32_bf16(a2, b2v, acc2, 0, 0, 0);
            acc3 = __builtin_amdgcn_mfma_f32_16x16x32_bf16(a3, b3v, acc3, 0, 0, 0);
        }
        #pragma unroll
        for (int reg = 0; reg < 4; reg++) {
            const int m = quad * 4 + reg;
            const float v = (acc0[reg] + acc1[reg]) + (acc2[reg] + acc3[reg]);
            out[(size_t)(b0 + m) * NC + w * 16 + l16] = v * invZ_s[m];
        }
    }
}

extern "C" void kernel_launch(void* const* d_in, const int* in_sizes, int n_in,
                              void* d_out, int out_size, void* d_ws, size_t ws_size,
                              hipStream_t stream) {
    const float* x     = (const float*)d_in[0];
    const float* Wfc   = (const float*)d_in[1];
    const float* bfc   = (const float*)d_in[2];
    const float* M     = (const float*)d_in[3];
    const float* wprev = (const float*)d_in[4];
    float* out = (float*)d_out;

    char* ws = (char*)d_ws;
    unsigned short* k_sw  = (unsigned short*)(ws);             // 4194304 B
    float*          scal  = (float*)(ws + 4194304);            // 524288 B
    float*          imn   = (float*)(ws + 4718592);            // 8192 B
    unsigned short* Mb_sw = (unsigned short*)(ws + 4726784);   // 524288 B
    unsigned short* Mt_sw = (unsigned short*)(ws + 5251072);   // 524288 B
    unsigned short* Wt_sw = (unsigned short*)(ws + 5775360);   // 294912 B

    hipLaunchKernelGGL(prep_all, dim3(NR + KCTRL), dim3(64), 0, stream,
                       M, Mb_sw, Mt_sw, imn, Wfc, Wt_sw);
    hipLaunchKernelGGL(fc_mfma, dim3(NB / 16), dim3(256), 0, stream, x, Wt_sw, bfc, k_sw, scal);
    hipLaunchKernelGGL(head_mfma, dim3(NB / 16), dim3(512), 0, stream,
                       Mb_sw, Mt_sw, imn, k_sw, scal, wprev, out);
}